// Round 12
// baseline (101.698 us; speedup 1.0000x reference)
//
#include <hip/hip_runtime.h>
#include <stdint.h>

#define B_ 64
#define T_ 4096
#define H_ 256
#define U_ 256

typedef float f32x4 __attribute__((ext_vector_type(4)));
typedef short short8 __attribute__((ext_vector_type(8)));
typedef unsigned int uint4v __attribute__((ext_vector_type(4)));

__device__ __forceinline__ short bf16rne(float f) {
    uint32_t x = __builtin_bit_cast(uint32_t, f);
    return (short)((x + 0x7FFFu + ((x >> 16) & 1u)) >> 16);
}

__device__ __forceinline__ float fast_tanh(float x) {
    float e = __expf(2.0f * x);
    return 1.0f - 2.0f * __builtin_amdgcn_rcpf(e + 1.0f);
}

// Barrier that orders LDS only (lgkmcnt); global loads stay in flight (R6-proven correct).
__device__ __forceinline__ void wg_barrier_lds() {
    asm volatile("s_waitcnt lgkmcnt(0)" ::: "memory");
    __builtin_amdgcn_sched_barrier(0);
    __builtin_amdgcn_s_barrier();
    __builtin_amdgcn_sched_barrier(0);
}

// pack 8 fp32 -> 8 bf16 (RNE) in 4 dwords via v_cvt_pk_bf16_f32
__device__ __forceinline__ uint4v pack_bf16x8(const f32x4 a, const f32x4 b) {
    uint32_t w0, w1, w2, w3;
    asm("v_cvt_pk_bf16_f32 %0, %1, %2" : "=v"(w0) : "v"(a[0]), "v"(a[1]));
    asm("v_cvt_pk_bf16_f32 %0, %1, %2" : "=v"(w1) : "v"(a[2]), "v"(a[3]));
    asm("v_cvt_pk_bf16_f32 %0, %1, %2" : "=v"(w2) : "v"(b[0]), "v"(b[1]));
    asm("v_cvt_pk_bf16_f32 %0, %1, %2" : "=v"(w3) : "v"(b[2]), "v"(b[3]));
    uint4v r; r[0] = w0; r[1] = w1; r[2] = w2; r[3] = w3;
    return r;
}

// ---- fused prep: blocks 0-255 convert W2 -> w2t[u][h] bf16; blocks 256-319 qproj ----
__global__ __launch_bounds__(256) void k_prep(const float* __restrict__ W2,
                                              uint16_t* __restrict__ w2t,
                                              const float* __restrict__ query,
                                              const float* __restrict__ W1,
                                              const float* __restrict__ b1,
                                              const float* __restrict__ b2,
                                              float* __restrict__ qpc) {
    if (blockIdx.x < 256) {
        int idx = blockIdx.x * 256 + threadIdx.x;
        int h = idx >> 8;
        int u = idx & 255;
        w2t[u * 256 + h] = (uint16_t)bf16rne(W2[idx]);
    } else {
        __shared__ float qrow[H_];
        int b = blockIdx.x - 256, u = threadIdx.x;
        qrow[u] = query[b * H_ + u];
        __syncthreads();
        float acc = b1[u] + b2[u];
#pragma unroll 8
        for (int h = 0; h < H_; ++h) acc += qrow[h] * W1[h * U_ + u];
        qpc[b * U_ + u] = acc;
    }
}

// ---------------- fused main: 512 thr / 8 waves, SINGLE barrier per tile ----------------
// R11 base (proven 92.7 us) with double-buffered Ab+red and ONE lgkm-only barrier per
// tile: MFMA(t) || stage(t+1) || consume(t-1) || prefetch(t+2) all in one region so
// the LDS, VALU, transcendental and HBM pipes overlap instead of phase-serializing
// (R3==R11 at different occupancy proved the limiter is pipe-sum, not latency).
// Every LDS hazard has exactly one barrier between writer and reader:
//   Ab[p] written R(t), read R(t+1);  red[p] written R(t), read R(t+1), rewritten R(t+2).
// vt single-slot time-share keeps regs ~124 <=128 ((512,2) cap, R1/R10-measured).
#define TR 32
#define NT 8
__global__ __launch_bounds__(512, 2) void k_main(const float* __restrict__ values,
                                                 const uint16_t* __restrict__ w2t,
                                                 const float* __restrict__ qpc,
                                                 const float* __restrict__ V,
                                                 float* __restrict__ score,
                                                 float* __restrict__ part_O,
                                                 float* __restrict__ part_s) {
    __shared__ __align__(16) char Ab[2][TR * 512]; // bf16 [32][256] x2, byte^=((row&7)<<4)
    __shared__ __align__(16) float red[2][TR][12]; // [parity][row][wave0..7], 48B rows
    __shared__ float Ored[TR][16][16];             // per-thread context partials (32 KB)
    __shared__ float sred[TR];

    const int tid = threadIdx.x;
    const int wg = blockIdx.x;          // 0..1023
    const int b = wg >> 4;
    const int chunk = (wg & 15) * (NT * TR);

    const int w = tid >> 6;             // wave 0..7
    const int l = tid & 63;
    const int c = l & 15;
    const int g = l >> 4;

    // A fragments (W2) in regs for whole kernel: 2 strips x 8 ks (64 VGPR)
    short8 afr[2][8];
#pragma unroll
    for (int s = 0; s < 2; ++s) {
        const uint16_t* ap = w2t + (size_t)(w * 32 + s * 16 + c) * 256 + g * 8;
#pragma unroll
        for (int ks = 0; ks < 8; ++ks) afr[s][ks] = *(const short8*)(ap + ks * 32);
    }
    float qv[2][4], vv[2][4];
#pragma unroll
    for (int s = 0; s < 2; ++s)
#pragma unroll
        for (int r = 0; r < 4; ++r) {
            int u = w * 32 + s * 16 + g * 4 + r;
            qv[s][r] = qpc[b * U_ + u];
            vv[s][r] = V[u];
        }

    const float* vbase = values + (size_t)b * T_ * H_;
    const int srow = tid >> 4;          // 0..31: row this thread stages/consumes
    const int q = tid & 15;             // 16B chunk within row
    const int sswz = (srow & 7) << 4;
    const int wroff = srow * 512 + ((q * 16) ^ sswz);   // +256 for the second 16B

    const float* sbase = vbase + (size_t)srow * H_ + q * 8;

    // single time-shared value slot (16 VGPR) + fp32 ctx accumulators
    f32x4 vt0, vt1, vt2, vt3;
    float Oacc[16];
#pragma unroll
    for (int j = 0; j < 16; ++j) Oacc[j] = 0.f;
    float sacc = 0.f;

    {   // prologue: tile 0 -> Ab[0]; tile 1 -> vt
        const float* nb = sbase + (size_t)chunk * H_;
        vt0 = *(const f32x4*)(nb);       vt1 = *(const f32x4*)(nb + 4);
        vt2 = *(const f32x4*)(nb + 128); vt3 = *(const f32x4*)(nb + 132);
        *(uint4v*)(Ab[0] + wroff)       = pack_bf16x8(vt0, vt1);
        *(uint4v*)(Ab[0] + wroff + 256) = pack_bf16x8(vt2, vt3);
        const float* nb1 = sbase + (size_t)(chunk + TR) * H_;
        vt0 = *(const f32x4*)(nb1);       vt1 = *(const f32x4*)(nb1 + 4);
        vt2 = *(const f32x4*)(nb1 + 128); vt3 = *(const f32x4*)(nb1 + 132);
    }

#pragma unroll
    for (int t = 0; t < NT; ++t) {
        wg_barrier_lds();   // single barrier: Ab[t&1]+red[(t-1)&1] ready, old readers done

        // ---- MFMA phase on tile t (reads Ab[t&1], writes red[t&1]) ----
#pragma unroll
        for (int sub = 0; sub < 2; ++sub) {
            const char* rp = Ab[t & 1] + (sub * 16 + c) * 512;
            const int swz = (c & 7) << 4;
            f32x4 acc0 = (f32x4)(0.0f);
            f32x4 acc1 = (f32x4)(0.0f);
#pragma unroll
            for (int ks = 0; ks < 8; ++ks) {
                short8 bf = *(const short8*)(rp + ((ks * 64 + g * 16) ^ swz));
                acc0 = __builtin_amdgcn_mfma_f32_16x16x32_bf16(afr[0][ks], bf, acc0, 0, 0, 0);
                acc1 = __builtin_amdgcn_mfma_f32_16x16x32_bf16(afr[1][ks], bf, acc1, 0, 0, 0);
            }
            float p = 0.f;
#pragma unroll
            for (int r = 0; r < 4; ++r) {
                p += fast_tanh(acc0[r] + qv[0][r]) * vv[0][r];
                p += fast_tanh(acc1[r] + qv[1][r]) * vv[1][r];
            }
            p += __shfl_xor(p, 16, 64);
            p += __shfl_xor(p, 32, 64);
            if (g == 0) red[t & 1][sub * 16 + c][w] = p;
        }

        // ---- stage tile t+1 (from vt) into Ab[(t+1)&1] ----
        if (t + 1 < NT) {
            char* dst = Ab[(t + 1) & 1] + wroff;
            *(uint4v*)(dst)       = pack_bf16x8(vt0, vt1);
            *(uint4v*)(dst + 256) = pack_bf16x8(vt2, vt3);
        }

        // ---- consume tile t-1: L2 re-read into freed vt slot + red[(t-1)&1] ----
        if (t > 0) {
            const float* rb = sbase + (size_t)(chunk + (t - 1) * TR) * H_;
            vt0 = *(const f32x4*)(rb);       vt1 = *(const f32x4*)(rb + 4);
            vt2 = *(const f32x4*)(rb + 128); vt3 = *(const f32x4*)(rb + 132);
            const float* rr = &red[(t - 1) & 1][srow][0];
            f32x4 r0 = *(const f32x4*)(rr);
            f32x4 r1 = *(const f32x4*)(rr + 4);
            float ssum = ((r0[0] + r0[1]) + (r0[2] + r0[3])) +
                         ((r1[0] + r1[1]) + (r1[2] + r1[3]));
            float wgt = __expf(ssum);
            if (q == 0) {
                sacc += wgt;
                score[(size_t)b * T_ + chunk + (t - 1) * TR + srow] = ssum;
            }
#pragma unroll
            for (int j = 0; j < 4; ++j) {
                Oacc[j]      += wgt * vt0[j];
                Oacc[4 + j]  += wgt * vt1[j];
                Oacc[8 + j]  += wgt * vt2[j];
                Oacc[12 + j] += wgt * vt3[j];
            }
        }

        // ---- prefetch tile t+2 (HBM) into vt ----
        if (t + 2 < NT) {
            const float* nb = sbase + (size_t)(chunk + (t + 2) * TR) * H_;
            vt0 = *(const f32x4*)(nb);       vt1 = *(const f32x4*)(nb + 4);
            vt2 = *(const f32x4*)(nb + 128); vt3 = *(const f32x4*)(nb + 132);
        }
    }
    __syncthreads();
    {   // final consume: tile NT-1 (red[(NT-1)&1]), re-read from L2
        const float* rb = sbase + (size_t)(chunk + (NT - 1) * TR) * H_;
        vt0 = *(const f32x4*)(rb);       vt1 = *(const f32x4*)(rb + 4);
        vt2 = *(const f32x4*)(rb + 128); vt3 = *(const f32x4*)(rb + 132);
        const float* rr = &red[(NT - 1) & 1][srow][0];
        f32x4 r0 = *(const f32x4*)(rr);
        f32x4 r1 = *(const f32x4*)(rr + 4);
        float ssum = ((r0[0] + r0[1]) + (r0[2] + r0[3])) +
                     ((r1[0] + r1[1]) + (r1[2] + r1[3]));
        float wgt = __expf(ssum);
        if (q == 0) {
            sacc += wgt;
            score[(size_t)b * T_ + chunk + (NT - 1) * TR + srow] = ssum;
        }
#pragma unroll
        for (int j = 0; j < 4; ++j) {
            Oacc[j]      += wgt * vt0[j];
            Oacc[4 + j]  += wgt * vt1[j];
            Oacc[8 + j]  += wgt * vt2[j];
            Oacc[12 + j] += wgt * vt3[j];
        }
    }
    // reduce per-thread context partials across the 32 rows
#pragma unroll
    for (int j = 0; j < 16; ++j) Ored[srow][q][j] = Oacc[j];
    if (q == 0) sred[srow] = sacc;
    __syncthreads();
    if (tid < 256) {
        int col = tid;
        int qq, jj;
        if (col < 128) { qq = col >> 3; jj = col & 7; }
        else           { qq = (col - 128) >> 3; jj = 8 + (col & 7); }
        float o = 0.f;
#pragma unroll
        for (int s = 0; s < TR; ++s) o += Ored[s][qq][jj];
        part_O[(size_t)wg * 256 + col] = o;
    }
    if (tid == 0) {
        float sb = 0.f;
#pragma unroll
        for (int s = 0; s < TR; ++s) sb += sred[s];
        part_s[wg] = sb;
    }
}

// ---------------- finish: reduce partials, write ctx + normalized weights ----------------
__global__ __launch_bounds__(256) void k_fin(const float* __restrict__ part_O,
                                             const float* __restrict__ part_s,
                                             const float* __restrict__ score,
                                             float* __restrict__ ctx,
                                             float* __restrict__ weights) {
    int b = blockIdx.x >> 3;
    int j = blockIdx.x & 7;
    int col = threadIdx.x;
    float sb = 0.f;
#pragma unroll
    for (int ch = 0; ch < 16; ++ch) sb += part_s[b * 16 + ch];
    float inv = 1.0f / sb;
    if (j == 0) {
        float o = 0.f;
#pragma unroll
        for (int ch = 0; ch < 16; ++ch) o += part_O[(size_t)(b * 16 + ch) * 256 + col];
        ctx[b * H_ + col] = o * inv;
    }
#pragma unroll
    for (int i = 0; i < 2; ++i) {
        int idx = j * 512 + i * 256 + col;
        float s = score[(size_t)b * T_ + idx];
        weights[(size_t)b * T_ + idx] = __expf(s) * inv;
    }
}

extern "C" void kernel_launch(void* const* d_in, const int* in_sizes, int n_in,
                              void* d_out, int out_size, void* d_ws, size_t ws_size,
                              hipStream_t stream) {
    const float* query  = (const float*)d_in[0];
    const float* values = (const float*)d_in[1];
    const float* W1     = (const float*)d_in[2];
    const float* b1     = (const float*)d_in[3];
    const float* W2     = (const float*)d_in[4];
    const float* b2     = (const float*)d_in[5];
    const float* V      = (const float*)d_in[6];
    // d_in[7] = bV: softmax is shift-invariant -> no effect on outputs.

    float* out = (float*)d_out;
    float* ctx = out;                    // [B,H]
    float* weights = out + B_ * H_;      // [B,T,1]

    char* ws = (char*)d_ws;
    uint16_t* w2t   = (uint16_t*)ws;                               // 128 KB
    float* qpc      = (float*)(ws + 131072);                       // 64 KB
    float* scorebuf = (float*)(ws + 131072 + 65536);               // 1 MB
    float* part_O   = (float*)(ws + 131072 + 65536 + 1048576);     // 1 MB
    float* part_s   = (float*)(ws + 131072 + 65536 + 2097152);     // 4 KB

    k_prep<<<dim3(320), dim3(256), 0, stream>>>(W2, w2t, query, W1, b1, b2, qpc);
    k_main<<<dim3(1024), dim3(512), 0, stream>>>(values, w2t, qpc, V, scorebuf,
                                                 part_O, part_s);
    k_fin<<<dim3(512), dim3(256), 0, stream>>>(part_O, part_s, scorebuf, ctx, weights);
}